// Round 9
// baseline (209.139 us; speedup 1.0000x reference)
//
#include <hip/hip_runtime.h>
#include <hip/hip_bf16.h>
#include <cstdint>
#include <cstddef>

#define NB   32
#define CIN  128
#define HWP  3136          // 56*56
#define KOC  256
#define NRS  9
#define PROW 3364          // 58*58 padded rows per (n,ck)
#define GUARD 256          // staging over-read guard rows at end of xt
#define AEL  12288         // elems per (ck,r,ot) A slab (24 KB)
#define BEL  8192          // elems per B window buffer = 256 rows * 32 (16 KB)

typedef __attribute__((ext_vector_type(8))) short  short8;
typedef __attribute__((ext_vector_type(4))) short  short4v;
typedef __attribute__((ext_vector_type(4))) float  float4v;

__device__ __forceinline__ unsigned short f2bf(float f) {
    union { float f; unsigned int u; } v; v.f = f;
    unsigned int u = v.u;
    u = u + 0x7fffu + ((u >> 16) & 1u);   // RNE
    return (unsigned short)(u >> 16);
}

// ---------------------------------------------------------------------------
// Fused prep kernel, three independent jobs (disjoint outputs, no ordering):
//   blocks [0, 1152):      W (OIHW fp32) -> wt2, layout
//                          [ck][r][ot][s][wm][i][quad][lr][e]
//                          (strides: ck 73728, r 24576, ot 12288, s 4096,
//                           wm 2048, i 512, quad 128, lr 8, e 1)
//                          so each (ck,r,ot) 24 KB A-slab stages LINEARLY
//                          into LDS via global_load_lds.
//   blocks [1152, 2816):   x NCHW fp32 -> xt[n][ck][p'][32c] bf16 halo layout
//   blocks [2816, 2930):   zero the 228 guard rows per (n,ck) slab
// ---------------------------------------------------------------------------
__global__ __launch_bounds__(256) void prep_kernel(const float* __restrict__ W,
                                                   unsigned short* __restrict__ wt2,
                                                   const float* __restrict__ x,
                                                   unsigned short* __restrict__ xt) {
    __shared__ unsigned short lds[32 * 260];
    int blk = blockIdx.x;
    int t   = threadIdx.x;

    if (blk < 1152) {
        // ---- wt2 part ----
        int idx  = blk * 256 + t;
        int e    = idx & 7;
        int lr   = (idx >> 3) & 15;
        int quad = (idx >> 7) & 3;
        int i    = (idx >> 9) & 3;
        int wm   = (idx >> 11) & 1;
        int rem  = idx >> 12;          // ck*18 + r*6 + ot*3 + s, 0..71
        int s    = rem % 3;
        int q    = rem / 3;            // ck*6 + r*2 + ot
        int ot   = q & 1;
        int r    = (q >> 1) % 3;
        int ck   = q / 6;
        int oc = ot * 128 + wm * 64 + i * 16 + lr;
        int c  = ck * 32 + quad * 8 + e;
        wt2[idx] = f2bf(W[((size_t)oc * CIN + c) * NRS + r * 3 + s]);
        return;
    }

    if (blk >= 2816) {
        // ---- guard-zero part: 128 slabs x 228 guard rows, 64 B each ----
        int g = (blk - 2816) * 256 + t;            // 0 .. 29183 (exact)
        int slab = g / 228;
        int gi   = g - slab * 228;
        int row;
        if (gi < 59)       row = gi;                               // top halo
        else if (gi < 169) { int k = gi - 59;                      // seam gaps
                             row = 115 + 58 * (k >> 1) + (k & 1); }
        else               row = 3305 + (gi - 169);                // bottom halo
        unsigned short* gr = xt + (size_t)slab * (PROW * 32) + (size_t)row * 32;
        short8 z = (short8)0;
        *(short8*)(gr +  0) = z;
        *(short8*)(gr +  8) = z;
        *(short8*)(gr + 16) = z;
        *(short8*)(gr + 24) = z;
        return;
    }

    // ---- xpose part (interior rows) ----
    int b    = blk - 1152;
    int tile = b % 13;
    int ck   = (b / 13) & 3;
    int n    = b / 52;
    int hw0  = tile * 256;
    int wv   = t >> 6;
    int lane = t & 63;

    const float* src = x + ((size_t)(n * CIN + ck * 32)) * HWP;
    #pragma unroll
    for (int pass = 0; pass < 8; ++pass) {
        int c  = pass * 4 + wv;
        int hw = hw0 + lane * 4;
        if (hw < HWP) {
            float4v v = *(const float4v*)(src + (size_t)c * HWP + hw);
            short4v s4;
            #pragma unroll
            for (int k = 0; k < 4; ++k) s4[k] = (short)f2bf(v[k]);
            *(short4v*)(&lds[c * 260 + lane * 4]) = s4;
        }
    }
    __syncthreads();

    int sub = t & 3;
    int hwl = t >> 2;
    unsigned short* dst = xt + ((size_t)(n * 4 + ck)) * PROW * 32;
    #pragma unroll
    for (int pass = 0; pass < 4; ++pass) {
        int hl = pass * 64 + hwl;
        int hw = hw0 + hl;
        if (hw < HWP) {
            short8 v;
            #pragma unroll
            for (int j = 0; j < 8; ++j)
                v[j] = (short)lds[(sub * 8 + j) * 260 + hl];
            int pr = hw + 59 + 2 * (hw / 56);
            *(short8*)(dst + (size_t)pr * 32 + sub * 8) = v;
        }
    }
}

// ---------------------------------------------------------------------------
// Stage one 24 KB A slab (one (ck,r,ot): 3 taps x 128 oc x 32 ch) into LDS,
// linear (wt2 layout pre-arranged so fragment order == linear order).
// 4 waves x 6 instructions, 1536 x 16B chunks.
// ---------------------------------------------------------------------------
__device__ __forceinline__ void stage_A(const unsigned short* src,
                                        unsigned short* lbase,
                                        int wv, int lane) {
    #pragma unroll
    for (int it = 0; it < 6; ++it) {
        int c0 = it * 256 + wv * 64;       // wave-uniform chunk base
        __builtin_amdgcn_global_load_lds(
            (const __attribute__((address_space(1))) void*)(src + (size_t)(c0 + lane) * 8),
            (__attribute__((address_space(3))) void*)(lbase + (size_t)c0 * 8), 16, 0, 0);
    }
}

// ---------------------------------------------------------------------------
// Stage one 256-row halo window (16 KB) into LDS via async global_load_lds.
// XOR swizzle: LDS slot (r,q) holds global 16B-chunk (r, q ^ ((r>>1)&3)).
// 4 waves x 4 instructions cover all 1024 slots.
// ---------------------------------------------------------------------------
__device__ __forceinline__ void stage_B(const unsigned short* gwin,
                                        unsigned short* lbase,
                                        int wv, int lane) {
    #pragma unroll
    for (int it = 0; it < 4; ++it) {
        int blk = it * 4 + wv;             // wave-chunk 0..15 (wave-uniform)
        int s   = blk * 64 + lane;         // slot 0..1023
        int r   = s >> 2;
        int q   = s & 3;
        int qs  = q ^ ((r >> 1) & 3);
        __builtin_amdgcn_global_load_lds(
            (const __attribute__((address_space(1))) void*)(gwin + r * 32 + qs * 8),
            (__attribute__((address_space(3))) void*)(lbase + (size_t)blk * 512), 16, 0, 0);
    }
}

__device__ __forceinline__ short8 ldb(const char* lb, int r, int quad) {
    int q = quad ^ ((r >> 1) & 3);
    return *(const short8*)(lb + r * 64 + q * 16);
}

// ---------------------------------------------------------------------------
// Implicit GEMM, pure-LDS inner loop: 128 oc x 128 px per block, 4 waves
// (2 oc x 2 px), wave tile 64x64 via 4x4 mfma_f32_16x16x32_bf16.
//
// r8 post-mortem (unit-corrected per-CU tally): at 64x32 wave tiles the
// kernel moves 11.1 MB of LDS per CU; at the measured b128 drain rate
// (~85 B/cyc/CU, m134) that is ~130k of the 170k kernel cycles -> the LDS
// read port, not latency, is now the wall. LDS bytes/FLOP ~ (M+N)/(M*N):
// 64x64 cuts traffic 1.5x vs 64x32. Register need (~105-120 est, +20
// safety -> ~140) forces the 170-reg cap: __launch_bounds__(256,3) ->
// 3 waves/SIMD -> 3 blocks/CU -> LDS <= 54.6 KB -> A and B both
// SINGLE-buffered (24 + 16 = 40 KB). Two barriers per group:
//   stage A(g) [+B at r==0] -> bar (all waves' DMA drained) -> compute
//   3 taps -> bar (reads done, safe to overwrite next group).
// The per-group staging-drain exposure (~500-900 cyc of L2 DMA) is covered
// by the other TWO resident blocks computing (r5's 2-block version lacked
// this); 12 waves/CU keeps the TLP that r8 proved necessary.
// Regs: acc 64 + af 16 + b 8 + addr ~25 ~= 113, cap 170, margin ~57 ->
// no spill (signature: WRITE_SIZE == 100352 KB exactly).
// ---------------------------------------------------------------------------
__global__ __launch_bounds__(256, 3) void gemm_kernel(const unsigned short* __restrict__ xt,
                                                      const unsigned short* __restrict__ wt2,
                                                      const float* __restrict__ bias,
                                                      float* __restrict__ out) {
    __shared__ unsigned short lds[20480];   // 40 KB: A@0 (12288 el), B@12288 (8192 el)

    int bx0 = blockIdx.x;                 // 25 pt x 32 n x 2 ot = 1600
    int bx  = (bx0 & 7) * 200 + (bx0 >> 3);   // XCD chunk swizzle (bijective)
    int ot  = bx & 1;
    int n   = (bx >> 1) & 31;
    int pt  = bx >> 6;
    int p0  = pt * 128;

    int t    = threadIdx.x;
    int wv   = t >> 6;                    // 0..3
    int lane = t & 63;
    int lr   = lane & 15;
    int quad = lane >> 4;
    int wm   = wv >> 1;                   // oc half (64 oc)
    int wn   = wv & 1;                    // px half (64 px)

    int prbase = p0 + 2 * (p0 / 56);      // = pr(p0) - 59, >= 0

    // per-j window row of the center tap (shift 0); clamped for tail tile
    int rb[4];
    #pragma unroll
    for (int j = 0; j < 4; ++j) {
        int hw  = p0 + wn * 64 + j * 16 + lr;
        int hwc = hw < HWP ? hw : (HWP - 1);
        rb[j] = hwc + 59 + 2 * (hwc / 56) - prbase;   // in [59, 193)
    }

    const unsigned short* xb = xt + (size_t)n * 4 * PROW * 32;
    const unsigned short* wb = wt2 + ot * AEL;        // + ck*73728 + r*24576

    float4v acc[4][4];
    #pragma unroll
    for (int i = 0; i < 4; ++i)
        #pragma unroll
        for (int j = 0; j < 4; ++j)
            acc[i][j] = (float4v){0.f, 0.f, 0.f, 0.f};

    for (int ck = 0; ck < 4; ++ck) {
        for (int r = 0; r < 3; ++r) {
            // stage this group's A slab (and B window at ck start) into the
            // single buffers; previous group's reads finished at the last
            // barrier, so overwrite is safe.
            stage_A(wb + (size_t)ck * 73728 + (size_t)r * 24576, lds, wv, lane);
            if (r == 0)
                stage_B(xb + (size_t)ck * (PROW * 32) + (size_t)prbase * 32,
                        lds + 12288, wv, lane);
            __syncthreads();   // every wave drained its own DMA -> data visible

            const unsigned short* A = lds + wm * 2048 + lane * 8;
            const char* lbB = (const char*)(lds + 12288);
            int sh0 = (r - 1) * 58;

            #pragma unroll
            for (int s = 0; s < 3; ++s) {
                int shift = sh0 + s - 1;           // = SH[r*3+s]
                short8 af[4];
                #pragma unroll
                for (int i = 0; i < 4; ++i)
                    af[i] = *(const short8*)(A + s * 4096 + i * 512);
                short8 bcur = ldb(lbB, rb[0] + shift, quad);
                __builtin_amdgcn_s_setprio(1);
                #pragma unroll
                for (int j = 0; j < 4; ++j) {
                    short8 bnext;
                    if (j < 3) bnext = ldb(lbB, rb[j + 1] + shift, quad);
                    #pragma unroll
                    for (int i = 0; i < 4; ++i)
                        acc[i][j] = __builtin_amdgcn_mfma_f32_16x16x32_bf16(
                            af[i], bcur, acc[i][j], 0, 0, 0);
                    if (j < 3) bcur = bnext;
                }
                __builtin_amdgcn_s_setprio(0);
            }
            __syncthreads();   // all waves done reading before next overwrite
        }
    }

    // epilogue: D row = oc (quad*4+reg), col = pixel (lane&15)
    float* orow = out + (size_t)n * KOC * HWP;
    #pragma unroll
    for (int i = 0; i < 4; ++i) {
        #pragma unroll
        for (int rr = 0; rr < 4; ++rr) {
            int oc = ot * 128 + wm * 64 + i * 16 + quad * 4 + rr;
            float bi = bias[oc];
            #pragma unroll
            for (int j = 0; j < 4; ++j) {
                int hw = p0 + wn * 64 + j * 16 + lr;
                if (hw < HWP)
                    orow[(size_t)oc * HWP + hw] = acc[i][j][rr] + bi;
            }
        }
    }
}

// ---------------------------------------------------------------------------
// Safety fallback if ws is too small: naive direct conv (exact fp32).
// ---------------------------------------------------------------------------
__global__ void naive_kernel(const float* __restrict__ x, const float* __restrict__ W,
                             const float* __restrict__ b, float* __restrict__ out) {
    size_t idx = (size_t)blockIdx.x * 256 + threadIdx.x;
    if (idx >= (size_t)NB * KOC * HWP) return;
    int w0 = (int)(idx % 56);
    int h0 = (int)((idx / 56) % 56);
    int k  = (int)((idx / HWP) % KOC);
    int n  = (int)(idx / ((size_t)HWP * KOC));
    float acc = b[k];
    for (int c = 0; c < CIN; ++c) {
        const float* xr = x + ((size_t)n * CIN + c) * HWP;
        const float* wr = W + ((size_t)k * CIN + c) * NRS;
        for (int r = 0; r < 3; ++r) {
            int h = h0 + r - 1;
            if ((unsigned)h >= 56u) continue;
            for (int s = 0; s < 3; ++s) {
                int w = w0 + s - 1;
                if ((unsigned)w >= 56u) continue;
                acc += xr[h * 56 + w] * wr[r * 3 + s];
            }
        }
    }
    out[idx] = acc;
}

extern "C" void kernel_launch(void* const* d_in, const int* in_sizes, int n_in,
                              void* d_out, int out_size, void* d_ws, size_t ws_size,
                              hipStream_t stream) {
    const float* x  = (const float*)d_in[0];
    const float* W  = (const float*)d_in[1];
    const float* b  = (const float*)d_in[2];
    float* out = (float*)d_out;

    const size_t wt_elems = (size_t)NRS * 4 * 2 * 2 * 4 * 4 * 16 * 8;   // 294912
    const size_t xt_elems = (size_t)NB * 4 * PROW * 32 + (size_t)GUARD * 32;
    const size_t need = (wt_elems + xt_elems) * sizeof(unsigned short); // ~28.2 MB

    if (ws_size < need) {
        size_t total = (size_t)NB * KOC * HWP;
        naive_kernel<<<(unsigned)((total + 255) / 256), 256, 0, stream>>>(x, W, b, out);
        return;
    }

    unsigned short* wt2 = (unsigned short*)d_ws;
    unsigned short* xt  = wt2 + wt_elems;        // 16B-aligned

    // prep zeroes only the 228 guard rows per slab (no full-buffer memset)
    prep_kernel<<<1152 + NB * 4 * 13 + 114, 256, 0, stream>>>(W, wt2, x, xt);
    gemm_kernel<<<1600, 256, 0, stream>>>(xt, wt2, b, out);
}